// Round 4
// baseline (489.422 us; speedup 1.0000x reference)
//
#include <hip/hip_runtime.h>
#include <stdint.h>

#define D_DIM 784
#define H_DIM 1024
#define B_DIM 256
#define NBIN  10
#define G_CH  8             // chunk length (i's per main block)
#define T_CH  98            // D_DIM / G_CH
#define BT    16            // batch tile per main block (fixed by MFMA M=16)
#define BF    2             // batch rows per k_pscan block
#define LOG2E 1.4426950408889634f

typedef _Float16 half8_t  __attribute__((ext_vector_type(8)));
typedef __fp16   fp16x2_t __attribute__((ext_vector_type(2)));
typedef float    float4_t __attribute__((ext_vector_type(4)));

// ---------- prep: Wt2[j][h] = W[h][j] * log2(e), LDS-tiled transpose ----------
__global__ void k_transpose(const float* __restrict__ W, float* __restrict__ Wt2) {
    __shared__ float t[64][65];
    int j0 = blockIdx.x * 64, h0 = blockIdx.y * 64;
    int tj = threadIdx.x & 63, tr = threadIdx.x >> 6;
    int j = j0 + tj;
    #pragma unroll
    for (int r = 0; r < 16; ++r) {
        int hh = tr * 16 + r;
        t[hh][tj] = (j < D_DIM) ? W[(size_t)(h0 + hh) * D_DIM + j] : 0.0f;
    }
    __syncthreads();
    #pragma unroll
    for (int r = 0; r < 16; ++r) {
        int jj = tr * 16 + r;
        int jo = j0 + jj;
        if (jo < D_DIM) Wt2[(size_t)jo * H_DIM + h0 + tj] = t[tj][jj] * LOG2E;
    }
}

// ---------- prep: V -> f16 MFMA B-fragment layout via LDS staging ----------
// VB[i][kk][lane][jj]: lane needs B[k = kk*32 + (lane>>4)*8 + jj][n = lane&15]
__global__ void k_vbprep(const float* __restrict__ V, _Float16* __restrict__ VB) {
    int i   = blockIdx.x;
    int tid = threadIdx.x;
    __shared__ __align__(16) float vsf[H_DIM * NBIN];   // 40 KB
    const float4* src = (const float4*)(V + (size_t)i * H_DIM * NBIN);
    #pragma unroll
    for (int q = 0; q < 10; ++q) {
        float4 v = src[q * 256 + tid];
        *((float4*)&vsf[(q * 256 + tid) * 4]) = v;
    }
    __syncthreads();
    #pragma unroll
    for (int q = 0; q < 8; ++q) {
        int pair = q * 256 + tid;          // (kk,l) pair 0..2047
        int kk = pair >> 6, l = pair & 63;
        int n = l & 15, hb = kk * 32 + ((l >> 4) & 3) * 8;
        union { _Float16 h[8]; uint4 u; } o;
        #pragma unroll
        for (int jj = 0; jj < 8; ++jj)
            o.h[jj] = (_Float16)((n < NBIN) ? vsf[(hb + jj) * NBIN + n] : 0.0f);
        ((uint4*)VB)[(size_t)i * 2048 + pair] = o.u;
    }
}

// ---------- fused partial-sum + exclusive scan: PA[t][b][h] = c*log2e + sum_{j<t*G} x*W2 ----------
template<typename CT>
__global__ void k_pscan(const float* __restrict__ Wt2, const int* __restrict__ x,
                        const float* __restrict__ c, CT* __restrict__ PA) {
    int b0 = blockIdx.x * BF;
    int h  = blockIdx.y * 256 + threadIdx.x;
    __shared__ float xs[BF][D_DIM];
    for (int q = threadIdx.x; q < BF * (D_DIM / 4); q += 256) {
        int bb = q / (D_DIM / 4), r = q % (D_DIM / 4);
        int4 xi = ((const int4*)(x + (size_t)(b0 + bb) * D_DIM))[r];
        float4 xf = make_float4((float)xi.x, (float)xi.y, (float)xi.z, (float)xi.w);
        *((float4*)&xs[bb][r * 4]) = xf;
    }
    float acc0 = c[h] * LOG2E, acc1 = acc0;
    __syncthreads();
    for (int t = 0; t < T_CH; ++t) {
        PA[((size_t)t * B_DIM + b0 + 0) * H_DIM + h] = (CT)acc0;
        PA[((size_t)t * B_DIM + b0 + 1) * H_DIM + h] = (CT)acc1;
        #pragma unroll
        for (int j = 0; j < G_CH; ++j) {
            float wv = Wt2[(size_t)(t * G_CH + j) * H_DIM + h];
            acc0 += xs[0][t * G_CH + j] * wv;
            acc1 += xs[1][t * G_CH + j] * wv;
        }
    }
}

// ---------- main fused kernel (round-2 structure, G_CH=8, high occupancy) ----------
template<typename CT>
__global__ __launch_bounds__(256, 6)
void k_main(const float* __restrict__ Wt2, const _Float16* __restrict__ VB,
            const CT* __restrict__ PA, const int* __restrict__ x,
            const float* __restrict__ bias, float* __restrict__ out) {
    int bt  = blockIdx.x;        // batch tile 0..15 (fast dim)
    int tc  = blockIdx.y;        // chunk 0..97
    int tid = threadIdx.x;
    int w   = tid >> 6;          // wave 0..3 (K-split of H)
    int l   = tid & 63;
    int bl  = l & 15;            // MFMA A row == batch row within tile
    int kg  = l >> 4;            // 0..3
    int bg  = bt * BT + bl;
    int i0  = tc * G_CH;

    __shared__ float red[4][64][5];                  // stride-5 pad: conflict-free (5.25 KB)
    __shared__ float bs[G_CH][16];                   // 0.5 KB
    __shared__ __align__(16) float plds[BT][NBIN][12]; // 7.7 KB

    {   // stage bias chunk
        int ii = tid >> 4, n = tid & 15;
        if (ii < G_CH) bs[ii][n] = (n < NBIN) ? bias[(size_t)(i0 + ii) * NBIN + n] : 0.0f;
    }

    // checkpoint a-state: thread owns h = w*256 + m*32 + kg*8 + j (MFMA A-frag order)
    float a[8][8];
    {
        const CT* src = PA + ((size_t)tc * B_DIM + bg) * H_DIM + w * 256 + kg * 8;
        #pragma unroll
        for (int m = 0; m < 8; ++m)
            #pragma unroll
            for (int j = 0; j < 8; ++j)
                a[m][j] = (float)src[m * 32 + j];
    }
    __syncthreads();

    const float4* wt4 = (const float4*)Wt2;
    const uint4* vbbase = (const uint4*)VB;
    #pragma unroll 1
    for (int ii = 0; ii < G_CH; ++ii) {
        int i = i0 + ii;
        float xvf = (float)x[(size_t)bg * D_DIM + i];

        // B-fragments for this wave's 8 k-steps
        uint4 vb[8];
        const uint4* vbp = vbbase + ((size_t)i * 32 + w * 8) * 64 + l;
        #pragma unroll
        for (int m = 0; m < 8; ++m) vb[m] = vbp[m * 64];

        float4_t cfrag = {0.f, 0.f, 0.f, 0.f};
        #pragma unroll
        for (int m = 0; m < 8; ++m) {
            // sigmoid of CURRENT a (pre-update) -> f16 A-frag
            union { half8_t h8; uint u32[4]; } af;
            #pragma unroll
            for (int p = 0; p < 4; ++p) {
                float s0 = __builtin_amdgcn_rcpf(1.0f + __builtin_amdgcn_exp2f(-a[m][2 * p]));
                float s1 = __builtin_amdgcn_rcpf(1.0f + __builtin_amdgcn_exp2f(-a[m][2 * p + 1]));
                union { fp16x2_t v; uint u; } cv;
                cv.v = __builtin_amdgcn_cvt_pkrtz(s0, s1);
                af.u32[p] = cv.u;
            }
            union { half8_t h8; uint4 u; } bf;
            bf.u = vb[m];
            cfrag = __builtin_amdgcn_mfma_f32_16x16x32_f16(af.h8, bf.h8, cfrag, 0, 0, 0);

            // rank-1 update for next i
            int hb = (w * 256 + kg * 8 + m * 32) >> 2;
            float4 w0 = wt4[(size_t)i * (H_DIM / 4) + hb];
            float4 w1 = wt4[(size_t)i * (H_DIM / 4) + hb + 1];
            a[m][0] += xvf * w0.x; a[m][1] += xvf * w0.y; a[m][2] += xvf * w0.z; a[m][3] += xvf * w0.w;
            a[m][4] += xvf * w1.x; a[m][5] += xvf * w1.y; a[m][6] += xvf * w1.z; a[m][7] += xvf * w1.w;
        }

        // cross-wave K reduction of C
        red[w][l][0] = cfrag[0]; red[w][l][1] = cfrag[1];
        red[w][l][2] = cfrag[2]; red[w][l][3] = cfrag[3];
        __syncthreads();
        // finalize C[batch = kg*4 + w][bin = bl]
        float tot = red[0][l][w] + red[1][l][w] + red[2][l][w] + red[3][l][w];
        int n = bl;
        float v = (n < NBIN) ? tot + bs[ii][n] : -3.0e38f;
        float vm = v;
        vm = fmaxf(vm, __shfl_xor(vm, 1));
        vm = fmaxf(vm, __shfl_xor(vm, 2));
        vm = fmaxf(vm, __shfl_xor(vm, 4));
        vm = fmaxf(vm, __shfl_xor(vm, 8));
        float e = __builtin_amdgcn_exp2f((v - vm) * LOG2E);
        float ss = e;
        ss += __shfl_xor(ss, 1); ss += __shfl_xor(ss, 2);
        ss += __shfl_xor(ss, 4); ss += __shfl_xor(ss, 8);
        float p = e * __builtin_amdgcn_rcpf(ss);
        if (n < NBIN) plds[kg * 4 + w][n][ii] = p;
        __syncthreads();   // red reusable next iter; plds complete at loop end
    }

    // coalesced chunk writeback: out[b][n][i0..i0+7]
    if (tid < BT * NBIN) {
        int bb = tid / NBIN, n = tid % NBIN;
        size_t base = ((size_t)(bt * BT + bb) * NBIN + n) * D_DIM + i0;
        #pragma unroll
        for (int q = 0; q < 2; ++q) {
            float4 v = *((float4*)&plds[bb][n][q * 4]);
            *((float4*)(out + base + q * 4)) = v;
        }
    }
}

extern "C" void kernel_launch(void* const* d_in, const int* in_sizes, int n_in,
                              void* d_out, int out_size, void* d_ws, size_t ws_size,
                              hipStream_t stream) {
    const int*   x    = (const int*)d_in[0];
    const float* W    = (const float*)d_in[1];
    const float* c    = (const float*)d_in[2];
    const float* V    = (const float*)d_in[3];
    const float* bias = (const float*)d_in[4];
    float* out = (float*)d_out;

    char* ws = (char*)d_ws;
    size_t off = 0;
    float* Wt2 = (float*)(ws + off);
    off += (size_t)D_DIM * H_DIM * sizeof(float);
    off = (off + 255) & ~(size_t)255;
    _Float16* VB = (_Float16*)(ws + off);
    off += (size_t)D_DIM * 32 * 64 * 8 * sizeof(_Float16);
    off = (off + 255) & ~(size_t)255;
    size_t pa_f32 = (size_t)T_CH * B_DIM * H_DIM * sizeof(float);
    bool f32ck = (off + pa_f32) <= ws_size;

    k_transpose<<<dim3(13, 16), 256, 0, stream>>>(W, Wt2);
    k_vbprep<<<dim3(D_DIM), 256, 0, stream>>>(V, VB);

    if (f32ck) {
        float* PA = (float*)(ws + off);
        k_pscan<float><<<dim3(B_DIM / BF, 4), 256, 0, stream>>>(Wt2, x, c, PA);
        k_main<float><<<dim3(B_DIM / BT, T_CH), 256, 0, stream>>>(Wt2, VB, PA, x, bias, out);
    } else {
        _Float16* PA = (_Float16*)(ws + off);
        k_pscan<_Float16><<<dim3(B_DIM / BF, 4), 256, 0, stream>>>(Wt2, x, c, PA);
        k_main<_Float16><<<dim3(B_DIM / BT, T_CH), 256, 0, stream>>>(Wt2, VB, PA, x, bias, out);
    }
}

// Round 5
// 265.565 us; speedup vs baseline: 1.8429x; 1.8429x over previous
//
#include <hip/hip_runtime.h>
#include <stdint.h>

#define D_DIM 784
#define H_DIM 1024
#define B_DIM 256
#define NBIN  10
#define G_CH  8             // chunk length (i's per main block)
#define T_CH  98            // D_DIM / G_CH
#define BT    16            // batch tile per main block (fixed by MFMA M=16)
#define BF    2             // batch rows per k_pscan block
#define LOG2E 1.4426950408889634f

typedef _Float16 half8_t  __attribute__((ext_vector_type(8)));
typedef __fp16   fp16x2_t __attribute__((ext_vector_type(2)));
typedef float    float4_t __attribute__((ext_vector_type(4)));

// ---------- prep: Wt2[j][h] = W[h][j] * log2(e), LDS-tiled transpose ----------
__global__ void k_transpose(const float* __restrict__ W, float* __restrict__ Wt2) {
    __shared__ float t[64][65];
    int j0 = blockIdx.x * 64, h0 = blockIdx.y * 64;
    int tj = threadIdx.x & 63, tr = threadIdx.x >> 6;
    int j = j0 + tj;
    #pragma unroll
    for (int r = 0; r < 16; ++r) {
        int hh = tr * 16 + r;
        t[hh][tj] = (j < D_DIM) ? W[(size_t)(h0 + hh) * D_DIM + j] : 0.0f;
    }
    __syncthreads();
    #pragma unroll
    for (int r = 0; r < 16; ++r) {
        int jj = tr * 16 + r;
        int jo = j0 + jj;
        if (jo < D_DIM) Wt2[(size_t)jo * H_DIM + h0 + tj] = t[tj][jj] * LOG2E;
    }
}

// ---------- prep: V -> f16 MFMA B-fragment layout via LDS staging ----------
// VB[i][kk][lane][jj]: lane needs B[k = kk*32 + (lane>>4)*8 + jj][n = lane&15]
__global__ void k_vbprep(const float* __restrict__ V, _Float16* __restrict__ VB) {
    int i   = blockIdx.x;
    int tid = threadIdx.x;
    __shared__ __align__(16) float vsf[H_DIM * NBIN];   // 40 KB
    const float4* src = (const float4*)(V + (size_t)i * H_DIM * NBIN);
    #pragma unroll
    for (int q = 0; q < 10; ++q) {
        float4 v = src[q * 256 + tid];
        *((float4*)&vsf[(q * 256 + tid) * 4]) = v;
    }
    __syncthreads();
    #pragma unroll
    for (int q = 0; q < 8; ++q) {
        int pair = q * 256 + tid;          // (kk,l) pair 0..2047
        int kk = pair >> 6, l = pair & 63;
        int n = l & 15, hb = kk * 32 + ((l >> 4) & 3) * 8;
        union { _Float16 h[8]; uint4 u; } o;
        #pragma unroll
        for (int jj = 0; jj < 8; ++jj)
            o.h[jj] = (_Float16)((n < NBIN) ? vsf[(hb + jj) * NBIN + n] : 0.0f);
        ((uint4*)VB)[(size_t)i * 2048 + pair] = o.u;
    }
}

// ---------- fused partial-sum + exclusive scan: PA[t][b][h] = c*log2e + sum_{j<t*G} x*W2 ----------
template<typename CT>
__global__ void k_pscan(const float* __restrict__ Wt2, const int* __restrict__ x,
                        const float* __restrict__ c, CT* __restrict__ PA) {
    int b0 = blockIdx.x * BF;
    int h  = blockIdx.y * 256 + threadIdx.x;
    __shared__ float xs[BF][D_DIM];
    for (int q = threadIdx.x; q < BF * (D_DIM / 4); q += 256) {
        int bb = q / (D_DIM / 4), r = q % (D_DIM / 4);
        int4 xi = ((const int4*)(x + (size_t)(b0 + bb) * D_DIM))[r];
        float4 xf = make_float4((float)xi.x, (float)xi.y, (float)xi.z, (float)xi.w);
        *((float4*)&xs[bb][r * 4]) = xf;
    }
    float acc0 = c[h] * LOG2E, acc1 = acc0;
    __syncthreads();
    for (int t = 0; t < T_CH; ++t) {
        PA[((size_t)t * B_DIM + b0 + 0) * H_DIM + h] = (CT)acc0;
        PA[((size_t)t * B_DIM + b0 + 1) * H_DIM + h] = (CT)acc1;
        #pragma unroll
        for (int j = 0; j < G_CH; ++j) {
            float wv = Wt2[(size_t)(t * G_CH + j) * H_DIM + h];
            acc0 += xs[0][t * G_CH + j] * wv;
            acc1 += xs[1][t * G_CH + j] * wv;
        }
    }
}

// ---------- main fused kernel (round-2 structure, G_CH=8, 4 blocks/CU) ----------
template<typename CT>
__global__ __launch_bounds__(256, 4)   // VGPR cap 128: natural ~76-90, NO spill
void k_main(const float* __restrict__ Wt2, const _Float16* __restrict__ VB,
            const CT* __restrict__ PA, const int* __restrict__ x,
            const float* __restrict__ bias, float* __restrict__ out) {
    int bt  = blockIdx.x;        // batch tile 0..15 (fast dim)
    int tc  = blockIdx.y;        // chunk 0..97
    int tid = threadIdx.x;
    int w   = tid >> 6;          // wave 0..3 (K-split of H)
    int l   = tid & 63;
    int bl  = l & 15;            // MFMA A row == batch row within tile
    int kg  = l >> 4;            // 0..3
    int bg  = bt * BT + bl;
    int i0  = tc * G_CH;

    __shared__ float red[4][64][5];                  // stride-5 pad: conflict-free (5.25 KB)
    __shared__ float bs[G_CH][16];                   // 0.5 KB
    __shared__ __align__(16) float plds[BT][NBIN][12]; // 7.7 KB

    {   // stage bias chunk
        int ii = tid >> 4, n = tid & 15;
        if (ii < G_CH) bs[ii][n] = (n < NBIN) ? bias[(size_t)(i0 + ii) * NBIN + n] : 0.0f;
    }

    // checkpoint a-state: thread owns h = w*256 + m*32 + kg*8 + j (MFMA A-frag order)
    float a[8][8];
    {
        const CT* src = PA + ((size_t)tc * B_DIM + bg) * H_DIM + w * 256 + kg * 8;
        #pragma unroll
        for (int m = 0; m < 8; ++m)
            #pragma unroll
            for (int j = 0; j < 8; ++j)
                a[m][j] = (float)src[m * 32 + j];
    }
    __syncthreads();

    const float4* wt4 = (const float4*)Wt2;
    const uint4* vbbase = (const uint4*)VB;
    #pragma unroll 1
    for (int ii = 0; ii < G_CH; ++ii) {
        int i = i0 + ii;
        float xvf = (float)x[(size_t)bg * D_DIM + i];

        // B-fragments for this wave's 8 k-steps
        uint4 vb[8];
        const uint4* vbp = vbbase + ((size_t)i * 32 + w * 8) * 64 + l;
        #pragma unroll
        for (int m = 0; m < 8; ++m) vb[m] = vbp[m * 64];

        float4_t cfrag = {0.f, 0.f, 0.f, 0.f};
        #pragma unroll
        for (int m = 0; m < 8; ++m) {
            // sigmoid of CURRENT a (pre-update) -> f16 A-frag
            union { half8_t h8; uint u32[4]; } af;
            #pragma unroll
            for (int p = 0; p < 4; ++p) {
                float s0 = __builtin_amdgcn_rcpf(1.0f + __builtin_amdgcn_exp2f(-a[m][2 * p]));
                float s1 = __builtin_amdgcn_rcpf(1.0f + __builtin_amdgcn_exp2f(-a[m][2 * p + 1]));
                union { fp16x2_t v; uint u; } cv;
                cv.v = __builtin_amdgcn_cvt_pkrtz(s0, s1);
                af.u32[p] = cv.u;
            }
            union { half8_t h8; uint4 u; } bf;
            bf.u = vb[m];
            cfrag = __builtin_amdgcn_mfma_f32_16x16x32_f16(af.h8, bf.h8, cfrag, 0, 0, 0);

            // rank-1 update for next i
            int hb = (w * 256 + kg * 8 + m * 32) >> 2;
            float4 w0 = wt4[(size_t)i * (H_DIM / 4) + hb];
            float4 w1 = wt4[(size_t)i * (H_DIM / 4) + hb + 1];
            a[m][0] += xvf * w0.x; a[m][1] += xvf * w0.y; a[m][2] += xvf * w0.z; a[m][3] += xvf * w0.w;
            a[m][4] += xvf * w1.x; a[m][5] += xvf * w1.y; a[m][6] += xvf * w1.z; a[m][7] += xvf * w1.w;
        }

        // cross-wave K reduction of C
        red[w][l][0] = cfrag[0]; red[w][l][1] = cfrag[1];
        red[w][l][2] = cfrag[2]; red[w][l][3] = cfrag[3];
        __syncthreads();
        // finalize C[batch = kg*4 + w][bin = bl]
        float tot = red[0][l][w] + red[1][l][w] + red[2][l][w] + red[3][l][w];
        int n = bl;
        float v = (n < NBIN) ? tot + bs[ii][n] : -3.0e38f;
        float vm = v;
        vm = fmaxf(vm, __shfl_xor(vm, 1));
        vm = fmaxf(vm, __shfl_xor(vm, 2));
        vm = fmaxf(vm, __shfl_xor(vm, 4));
        vm = fmaxf(vm, __shfl_xor(vm, 8));
        float e = __builtin_amdgcn_exp2f((v - vm) * LOG2E);
        float ss = e;
        ss += __shfl_xor(ss, 1); ss += __shfl_xor(ss, 2);
        ss += __shfl_xor(ss, 4); ss += __shfl_xor(ss, 8);
        float p = e * __builtin_amdgcn_rcpf(ss);
        if (n < NBIN) plds[kg * 4 + w][n][ii] = p;
        __syncthreads();   // red reusable next iter; plds complete at loop end
    }

    // coalesced chunk writeback: out[b][n][i0..i0+7]
    if (tid < BT * NBIN) {
        int bb = tid / NBIN, n = tid % NBIN;
        size_t base = ((size_t)(bt * BT + bb) * NBIN + n) * D_DIM + i0;
        #pragma unroll
        for (int q = 0; q < 2; ++q) {
            float4 v = *((float4*)&plds[bb][n][q * 4]);
            *((float4*)(out + base + q * 4)) = v;
        }
    }
}

extern "C" void kernel_launch(void* const* d_in, const int* in_sizes, int n_in,
                              void* d_out, int out_size, void* d_ws, size_t ws_size,
                              hipStream_t stream) {
    const int*   x    = (const int*)d_in[0];
    const float* W    = (const float*)d_in[1];
    const float* c    = (const float*)d_in[2];
    const float* V    = (const float*)d_in[3];
    const float* bias = (const float*)d_in[4];
    float* out = (float*)d_out;

    char* ws = (char*)d_ws;
    size_t off = 0;
    float* Wt2 = (float*)(ws + off);
    off += (size_t)D_DIM * H_DIM * sizeof(float);
    off = (off + 255) & ~(size_t)255;
    _Float16* VB = (_Float16*)(ws + off);
    off += (size_t)D_DIM * 32 * 64 * 8 * sizeof(_Float16);
    off = (off + 255) & ~(size_t)255;
    size_t pa_f32 = (size_t)T_CH * B_DIM * H_DIM * sizeof(float);
    bool f32ck = (off + pa_f32) <= ws_size;

    k_transpose<<<dim3(13, 16), 256, 0, stream>>>(W, Wt2);
    k_vbprep<<<dim3(D_DIM), 256, 0, stream>>>(V, VB);

    if (f32ck) {
        float* PA = (float*)(ws + off);
        k_pscan<float><<<dim3(B_DIM / BF, 4), 256, 0, stream>>>(Wt2, x, c, PA);
        k_main<float><<<dim3(B_DIM / BT, T_CH), 256, 0, stream>>>(Wt2, VB, PA, x, bias, out);
    } else {
        _Float16* PA = (_Float16*)(ws + off);
        k_pscan<_Float16><<<dim3(B_DIM / BF, 4), 256, 0, stream>>>(Wt2, x, c, PA);
        k_main<_Float16><<<dim3(B_DIM / BT, T_CH), 256, 0, stream>>>(Wt2, VB, PA, x, bias, out);
    }
}

// Round 6
// 210.392 us; speedup vs baseline: 2.3262x; 1.2622x over previous
//
#include <hip/hip_runtime.h>
#include <stdint.h>

#define D_DIM 784
#define H_DIM 1024
#define B_DIM 256
#define NBIN  10
#define G_CH  8             // chunk length (i's per main block)
#define T_CH  98            // D_DIM / G_CH
#define BT    16            // batch tile per main block (fixed by MFMA M=16)
#define BF    2             // batch rows per k_pscan block
#define LOG2E 1.4426950408889634f

typedef _Float16 half8_t  __attribute__((ext_vector_type(8)));
typedef __fp16   fp16x2_t __attribute__((ext_vector_type(2)));
typedef float    float4_t __attribute__((ext_vector_type(4)));

// ---------- prep: Wt2[j][h] = W[h][j] * log2(e), LDS-tiled transpose ----------
__global__ void k_transpose(const float* __restrict__ W, float* __restrict__ Wt2) {
    __shared__ float t[64][65];
    int j0 = blockIdx.x * 64, h0 = blockIdx.y * 64;
    int tj = threadIdx.x & 63, tr = threadIdx.x >> 6;
    int j = j0 + tj;
    #pragma unroll
    for (int r = 0; r < 16; ++r) {
        int hh = tr * 16 + r;
        t[hh][tj] = (j < D_DIM) ? W[(size_t)(h0 + hh) * D_DIM + j] : 0.0f;
    }
    __syncthreads();
    #pragma unroll
    for (int r = 0; r < 16; ++r) {
        int jj = tr * 16 + r;
        int jo = j0 + jj;
        if (jo < D_DIM) Wt2[(size_t)jo * H_DIM + h0 + tj] = t[tj][jj] * LOG2E;
    }
}

// ---------- prep: V -> f16 MFMA B-fragment layout via LDS staging ----------
// VB[i][kk][lane][jj]: lane needs B[k = kk*32 + (lane>>4)*8 + jj][n = lane&15]
__global__ void k_vbprep(const float* __restrict__ V, _Float16* __restrict__ VB) {
    int i   = blockIdx.x;
    int tid = threadIdx.x;
    __shared__ __align__(16) float vsf[H_DIM * NBIN];   // 40 KB
    const float4* src = (const float4*)(V + (size_t)i * H_DIM * NBIN);
    #pragma unroll
    for (int q = 0; q < 10; ++q) {
        float4 v = src[q * 256 + tid];
        *((float4*)&vsf[(q * 256 + tid) * 4]) = v;
    }
    __syncthreads();
    #pragma unroll
    for (int q = 0; q < 8; ++q) {
        int pair = q * 256 + tid;          // (kk,l) pair 0..2047
        int kk = pair >> 6, l = pair & 63;
        int n = l & 15, hb = kk * 32 + ((l >> 4) & 3) * 8;
        union { _Float16 h[8]; uint4 u; } o;
        #pragma unroll
        for (int jj = 0; jj < 8; ++jj)
            o.h[jj] = (_Float16)((n < NBIN) ? vsf[(hb + jj) * NBIN + n] : 0.0f);
        ((uint4*)VB)[(size_t)i * 2048 + pair] = o.u;
    }
}

// ---------- fused partial-sum + exclusive scan: PA[t][b][h] = c*log2e + sum_{j<t*G} x*W2 ----------
template<typename CT>
__global__ void k_pscan(const float* __restrict__ Wt2, const int* __restrict__ x,
                        const float* __restrict__ c, CT* __restrict__ PA) {
    int b0 = blockIdx.x * BF;
    int h  = blockIdx.y * 256 + threadIdx.x;
    __shared__ float xs[BF][D_DIM];
    for (int q = threadIdx.x; q < BF * (D_DIM / 4); q += 256) {
        int bb = q / (D_DIM / 4), r = q % (D_DIM / 4);
        int4 xi = ((const int4*)(x + (size_t)(b0 + bb) * D_DIM))[r];
        float4 xf = make_float4((float)xi.x, (float)xi.y, (float)xi.z, (float)xi.w);
        *((float4*)&xs[bb][r * 4]) = xf;
    }
    float acc0 = c[h] * LOG2E, acc1 = acc0;
    __syncthreads();
    for (int t = 0; t < T_CH; ++t) {
        PA[((size_t)t * B_DIM + b0 + 0) * H_DIM + h] = (CT)acc0;
        PA[((size_t)t * B_DIM + b0 + 1) * H_DIM + h] = (CT)acc1;
        #pragma unroll
        for (int j = 0; j < G_CH; ++j) {
            float wv = Wt2[(size_t)(t * G_CH + j) * H_DIM + h];
            acc0 += xs[0][t * G_CH + j] * wv;
            acc1 += xs[1][t * G_CH + j] * wv;
        }
    }
}

// ---------- main fused kernel (round-2 structure, G_CH=8) ----------
// __launch_bounds__(256,3): empirical compiler cap ≈ 256/N -> 85; lands at 76 VGPR,
// zero spill (round-2 measured). HW still gives 4 waves/SIMD at 76 VGPR.
template<typename CT>
__global__ __launch_bounds__(256, 3)
void k_main(const float* __restrict__ Wt2, const _Float16* __restrict__ VB,
            const CT* __restrict__ PA, const int* __restrict__ x,
            const float* __restrict__ bias, float* __restrict__ out) {
    int bt  = blockIdx.x;        // batch tile 0..15 (fast dim)
    int tc  = blockIdx.y;        // chunk 0..97
    int tid = threadIdx.x;
    int w   = tid >> 6;          // wave 0..3 (K-split of H)
    int l   = tid & 63;
    int bl  = l & 15;            // MFMA A row == batch row within tile
    int kg  = l >> 4;            // 0..3
    int bg  = bt * BT + bl;
    int i0  = tc * G_CH;

    __shared__ float red[4][64][5];                  // stride-5 pad: conflict-free (5.25 KB)
    __shared__ float bs[G_CH][16];                   // 0.5 KB
    __shared__ __align__(16) float plds[BT][NBIN][12]; // 7.7 KB

    {   // stage bias chunk
        int ii = tid >> 4, n = tid & 15;
        if (ii < G_CH) bs[ii][n] = (n < NBIN) ? bias[(size_t)(i0 + ii) * NBIN + n] : 0.0f;
    }

    // checkpoint a-state: thread owns h = w*256 + m*32 + kg*8 + j (MFMA A-frag order)
    float a[8][8];
    {
        const CT* src = PA + ((size_t)tc * B_DIM + bg) * H_DIM + w * 256 + kg * 8;
        #pragma unroll
        for (int m = 0; m < 8; ++m)
            #pragma unroll
            for (int j = 0; j < 8; ++j)
                a[m][j] = (float)src[m * 32 + j];
    }
    __syncthreads();

    const float4* wt4 = (const float4*)Wt2;
    const uint4* vbbase = (const uint4*)VB;
    #pragma unroll 1
    for (int ii = 0; ii < G_CH; ++ii) {
        int i = i0 + ii;
        float xvf = (float)x[(size_t)bg * D_DIM + i];

        // B-fragments for this wave's 8 k-steps
        uint4 vb[8];
        const uint4* vbp = vbbase + ((size_t)i * 32 + w * 8) * 64 + l;
        #pragma unroll
        for (int m = 0; m < 8; ++m) vb[m] = vbp[m * 64];

        float4_t cfrag = {0.f, 0.f, 0.f, 0.f};
        #pragma unroll
        for (int m = 0; m < 8; ++m) {
            // sigmoid of CURRENT a (pre-update) -> f16 A-frag
            union { half8_t h8; uint u32[4]; } af;
            #pragma unroll
            for (int p = 0; p < 4; ++p) {
                float s0 = __builtin_amdgcn_rcpf(1.0f + __builtin_amdgcn_exp2f(-a[m][2 * p]));
                float s1 = __builtin_amdgcn_rcpf(1.0f + __builtin_amdgcn_exp2f(-a[m][2 * p + 1]));
                union { fp16x2_t v; uint u; } cv;
                cv.v = __builtin_amdgcn_cvt_pkrtz(s0, s1);
                af.u32[p] = cv.u;
            }
            union { half8_t h8; uint4 u; } bf;
            bf.u = vb[m];
            cfrag = __builtin_amdgcn_mfma_f32_16x16x32_f16(af.h8, bf.h8, cfrag, 0, 0, 0);

            // rank-1 update for next i
            int hb = (w * 256 + kg * 8 + m * 32) >> 2;
            float4 w0 = wt4[(size_t)i * (H_DIM / 4) + hb];
            float4 w1 = wt4[(size_t)i * (H_DIM / 4) + hb + 1];
            a[m][0] += xvf * w0.x; a[m][1] += xvf * w0.y; a[m][2] += xvf * w0.z; a[m][3] += xvf * w0.w;
            a[m][4] += xvf * w1.x; a[m][5] += xvf * w1.y; a[m][6] += xvf * w1.z; a[m][7] += xvf * w1.w;
        }

        // cross-wave K reduction of C
        red[w][l][0] = cfrag[0]; red[w][l][1] = cfrag[1];
        red[w][l][2] = cfrag[2]; red[w][l][3] = cfrag[3];
        __syncthreads();
        // finalize C[batch = kg*4 + w][bin = bl]
        float tot = red[0][l][w] + red[1][l][w] + red[2][l][w] + red[3][l][w];
        int n = bl;
        float v = (n < NBIN) ? tot + bs[ii][n] : -3.0e38f;
        float vm = v;
        vm = fmaxf(vm, __shfl_xor(vm, 1));
        vm = fmaxf(vm, __shfl_xor(vm, 2));
        vm = fmaxf(vm, __shfl_xor(vm, 4));
        vm = fmaxf(vm, __shfl_xor(vm, 8));
        float e = __builtin_amdgcn_exp2f((v - vm) * LOG2E);
        float ss = e;
        ss += __shfl_xor(ss, 1); ss += __shfl_xor(ss, 2);
        ss += __shfl_xor(ss, 4); ss += __shfl_xor(ss, 8);
        float p = e * __builtin_amdgcn_rcpf(ss);
        if (n < NBIN) plds[kg * 4 + w][n][ii] = p;
        __syncthreads();   // red reusable next iter; plds complete at loop end
    }

    // coalesced chunk writeback: out[b][n][i0..i0+7]
    if (tid < BT * NBIN) {
        int bb = tid / NBIN, n = tid % NBIN;
        size_t base = ((size_t)(bt * BT + bb) * NBIN + n) * D_DIM + i0;
        #pragma unroll
        for (int q = 0; q < 2; ++q) {
            float4 v = *((float4*)&plds[bb][n][q * 4]);
            *((float4*)(out + base + q * 4)) = v;
        }
    }
}

extern "C" void kernel_launch(void* const* d_in, const int* in_sizes, int n_in,
                              void* d_out, int out_size, void* d_ws, size_t ws_size,
                              hipStream_t stream) {
    const int*   x    = (const int*)d_in[0];
    const float* W    = (const float*)d_in[1];
    const float* c    = (const float*)d_in[2];
    const float* V    = (const float*)d_in[3];
    const float* bias = (const float*)d_in[4];
    float* out = (float*)d_out;

    char* ws = (char*)d_ws;
    size_t off = 0;
    float* Wt2 = (float*)(ws + off);
    off += (size_t)D_DIM * H_DIM * sizeof(float);
    off = (off + 255) & ~(size_t)255;
    _Float16* VB = (_Float16*)(ws + off);
    off += (size_t)D_DIM * 32 * 64 * 8 * sizeof(_Float16);
    off = (off + 255) & ~(size_t)255;
    size_t pa_f32 = (size_t)T_CH * B_DIM * H_DIM * sizeof(float);
    bool f32ck = (off + pa_f32) <= ws_size;

    k_transpose<<<dim3(13, 16), 256, 0, stream>>>(W, Wt2);
    k_vbprep<<<dim3(D_DIM), 256, 0, stream>>>(V, VB);

    if (f32ck) {
        float* PA = (float*)(ws + off);
        k_pscan<float><<<dim3(B_DIM / BF, 4), 256, 0, stream>>>(Wt2, x, c, PA);
        k_main<float><<<dim3(B_DIM / BT, T_CH), 256, 0, stream>>>(Wt2, VB, PA, x, bias, out);
    } else {
        _Float16* PA = (_Float16*)(ws + off);
        k_pscan<_Float16><<<dim3(B_DIM / BF, 4), 256, 0, stream>>>(Wt2, x, c, PA);
        k_main<_Float16><<<dim3(B_DIM / BT, T_CH), 256, 0, stream>>>(Wt2, VB, PA, x, bias, out);
    }
}